// Round 1
// baseline (207.840 us; speedup 1.0000x reference)
//
#include <hip/hip_runtime.h>
#include <math.h>

#define Bb   4
#define Nn   2048
#define Dd   256
#define Hh   4
#define HDd  64
#define BN   (Bb * Nn)

typedef float v4f __attribute__((ext_vector_type(4)));
typedef short v8s __attribute__((ext_vector_type(8)));

__device__ __forceinline__ unsigned rne_bf16(float f) {
    unsigned u = __float_as_uint(f);
    u += 0x7fffu + ((u >> 16) & 1u);
    return u >> 16;
}

// ---------------------------------------------------------------------------
// Kernel 1: h = x @ W.T via MFMA, hi/lo bf16 split (err ~2^-17).  UNCHANGED.
// Block = 256 thr (4 waves), C-tile 64m x 64n (n-tile == one head), grid 512.
// Epilogue: scores s_src/s_dst written TRANSPOSED [h][bn]; h -> bf16
// TRANSPOSED-TILED hbf [b][jb(64)][hd(256)][j(32)]  (== MFMA B-frag layout).
// ---------------------------------------------------------------------------
__global__ __launch_bounds__(256, 2) void k_gemm(const float* __restrict__ x,
                                                 const float* __restrict__ W,
                                                 const float* __restrict__ a_src,
                                                 const float* __restrict__ a_dst,
                                                 unsigned short* __restrict__ hbf,
                                                 float* __restrict__ ssrc,
                                                 float* __restrict__ sdst) {
    __shared__ __align__(16) unsigned short xs[2][64 * 72];  // hi, lo  (T reuses xs)
    __shared__ __align__(16) unsigned short wsm[2][64 * 72];
    __shared__ float asd[128];

    const int tid = threadIdx.x;
    const int m0 = (int)(blockIdx.x >> 2) * 64;
    const int head = (int)blockIdx.x & 3;
    const int n0 = head * 64;
    const int b = m0 >> 11;
    const int i0loc = m0 & 2047;

    if (tid < 128) {
        int sel = tid >> 6, d = tid & 63;
        asd[tid] = sel ? a_dst[n0 + d] : a_src[n0 + d];
    }

    const int wv = tid >> 6, ln = tid & 63, l15 = ln & 15, l4 = ln >> 4;
    const int mh = wv >> 1, nh = wv & 1;
    const int srow = tid >> 2, kq = (tid & 3) * 16;

    v4f acc[2][2];
#pragma unroll
    for (int g = 0; g < 2; ++g)
#pragma unroll
        for (int t = 0; t < 2; ++t) acc[g][t] = (v4f){0.f, 0.f, 0.f, 0.f};

    for (int st = 0; st < 4; ++st) {
        const int k0 = st * 64;
        __syncthreads();
        // ---- stage x and W tiles as bf16 hi/lo ----
        {
            float xf[16], wf[16];
            const float* xp = x + (size_t)(m0 + srow) * Dd + k0 + kq;
            const float* wp = W + (size_t)(n0 + srow) * Dd + k0 + kq;
#pragma unroll
            for (int q = 0; q < 4; ++q) {
                *(float4*)&xf[q * 4] = *(const float4*)(xp + q * 4);
                *(float4*)&wf[q * 4] = *(const float4*)(wp + q * 4);
            }
            unsigned xh[8], xl[8], wh[8], wl[8];
#pragma unroll
            for (int j = 0; j < 8; ++j) {
                unsigned h0 = rne_bf16(xf[2 * j]), h1 = rne_bf16(xf[2 * j + 1]);
                float l0 = xf[2 * j] - __uint_as_float(h0 << 16);
                float l1 = xf[2 * j + 1] - __uint_as_float(h1 << 16);
                xh[j] = h0 | (h1 << 16);
                xl[j] = rne_bf16(l0) | (rne_bf16(l1) << 16);
                unsigned g0 = rne_bf16(wf[2 * j]), g1 = rne_bf16(wf[2 * j + 1]);
                float m0f = wf[2 * j] - __uint_as_float(g0 << 16);
                float m1f = wf[2 * j + 1] - __uint_as_float(g1 << 16);
                wh[j] = g0 | (g1 << 16);
                wl[j] = rne_bf16(m0f) | (rne_bf16(m1f) << 16);
            }
            *(uint4*)(xs[0] + srow * 72 + kq)     = make_uint4(xh[0], xh[1], xh[2], xh[3]);
            *(uint4*)(xs[0] + srow * 72 + kq + 8) = make_uint4(xh[4], xh[5], xh[6], xh[7]);
            *(uint4*)(xs[1] + srow * 72 + kq)     = make_uint4(xl[0], xl[1], xl[2], xl[3]);
            *(uint4*)(xs[1] + srow * 72 + kq + 8) = make_uint4(xl[4], xl[5], xl[6], xl[7]);
            *(uint4*)(wsm[0] + srow * 72 + kq)     = make_uint4(wh[0], wh[1], wh[2], wh[3]);
            *(uint4*)(wsm[0] + srow * 72 + kq + 8) = make_uint4(wh[4], wh[5], wh[6], wh[7]);
            *(uint4*)(wsm[1] + srow * 72 + kq)     = make_uint4(wl[0], wl[1], wl[2], wl[3]);
            *(uint4*)(wsm[1] + srow * 72 + kq + 8) = make_uint4(wl[4], wl[5], wl[6], wl[7]);
        }
        __syncthreads();
        // ---- MFMA: wave (mh, nh) owns 2x2 16-tiles ----
        {
            v8s ah[2][2], al[2][2], bh_[2][2], bl_[2][2];
#pragma unroll
            for (int g = 0; g < 2; ++g)
#pragma unroll
                for (int kh = 0; kh < 2; ++kh) {
                    int ro = (mh * 32 + g * 16 + l15) * 72 + kh * 32 + l4 * 8;
                    ah[g][kh] = *(const v8s*)(xs[0] + ro);
                    al[g][kh] = *(const v8s*)(xs[1] + ro);
                }
#pragma unroll
            for (int t = 0; t < 2; ++t)
#pragma unroll
                for (int kh = 0; kh < 2; ++kh) {
                    int ro = (nh * 32 + t * 16 + l15) * 72 + kh * 32 + l4 * 8;
                    bh_[t][kh] = *(const v8s*)(wsm[0] + ro);
                    bl_[t][kh] = *(const v8s*)(wsm[1] + ro);
                }
#pragma unroll
            for (int g = 0; g < 2; ++g)
#pragma unroll
                for (int t = 0; t < 2; ++t)
#pragma unroll
                    for (int kh = 0; kh < 2; ++kh) {
                        acc[g][t] = __builtin_amdgcn_mfma_f32_16x16x32_bf16(ah[g][kh], bh_[t][kh], acc[g][t], 0, 0, 0);
                        acc[g][t] = __builtin_amdgcn_mfma_f32_16x16x32_bf16(al[g][kh], bh_[t][kh], acc[g][t], 0, 0, 0);
                        acc[g][t] = __builtin_amdgcn_mfma_f32_16x16x32_bf16(ah[g][kh], bl_[t][kh], acc[g][t], 0, 0, 0);
                    }
        }
    }

    // ---- epilogue: C -> T[d][m] (stride 67) ----
    __syncthreads();
    float* T = (float*)&xs[0][0];   // 64*67*4 = 17168 B
#pragma unroll
    for (int g = 0; g < 2; ++g)
#pragma unroll
        for (int t = 0; t < 2; ++t)
#pragma unroll
            for (int r = 0; r < 4; ++r) {
                int d = nh * 32 + t * 16 + l15;
                int m = mh * 32 + g * 16 + l4 * 4 + r;
                T[d * 67 + m] = acc[g][t][r];
            }
    __syncthreads();
    if (tid < 128) {
        // scores -> TRANSPOSED [h][bn]
        int m = tid & 63, sel = tid >> 6;
        float s = 0.f;
#pragma unroll
        for (int d = 0; d < 64; ++d) s += T[d * 67 + m] * asd[sel * 64 + d];
        (sel ? sdst : ssrc)[(size_t)head * BN + (size_t)b * Nn + i0loc + m] = s;
        // hbf pack
        int dloc = tid >> 1, jh = tid & 1;
        const float* row = T + dloc * 67 + jh * 32;
        unsigned pk[16];
#pragma unroll
        for (int jj = 0; jj < 16; ++jj)
            pk[jj] = rne_bf16(row[jj * 2]) | (rne_bf16(row[jj * 2 + 1]) << 16);
        unsigned short* dst = hbf +
            ((size_t)((b * 64 + (i0loc >> 5) + jh) * 256 + head * HDd + dloc)) * 32;
        uint4* d4 = (uint4*)dst;
        d4[0] = make_uint4(pk[0], pk[1], pk[2], pk[3]);
        d4[1] = make_uint4(pk[4], pk[5], pk[6], pk[7]);
        d4[2] = make_uint4(pk[8], pk[9], pk[10], pk[11]);
        d4[3] = make_uint4(pk[12], pk[13], pk[14], pk[15]);
    }
}

// ---------------------------------------------------------------------------
// Kernel 2 (v2): barrier-free, LDS-free register pipeline.
// Key idea: a wave owns (head h, 16 i-rows); lane (l15,l4) of the wave
// computes w~[i=l15-row][j=l4*8..+8] — which IS the MFMA A-fragment
// layout (A[m=l&15][k=(l>>4)*8+e]).  So gen happens straight into the
// a-frag registers: no LDS staging, no __syncthreads, no bank conflicts.
// Each wave covers the full d-extent (4 d-tiles) of its head, so z needs
// only 2 ones-MFMAs/step (old structure did 4x redundant z work).
// All step inputs (adj, sdst, B-frags from hbf) are register-ping-pong
// prefetched one step ahead; every wave runs fully independently.
// Block = 256 thr = 4 waves = (2 heads of hp) x (2 i-subtiles), i-tile 32.
// Grid 512 = (b, i-tile) x hp, XCD-paired so hp-twins share adj in L2.
// Numerics are bit-identical to v1 (same gen chain, same j-accum order).
// ---------------------------------------------------------------------------
__global__ __launch_bounds__(256, 2) void k_aggr(const unsigned short* __restrict__ hbf,
                                                 const float* __restrict__ adj,
                                                 const float* __restrict__ ssrc,
                                                 const float* __restrict__ sdst,
                                                 float* __restrict__ out) {
    const int tid = threadIdx.x;
    const int bid = (int)blockIdx.x;
    const int hp  = (bid >> 3) & 1;                  // head pair
    const int lin = (bid & 7) | ((bid >> 4) << 3);   // XCD-paired (b, i-tile)
    const int b  = lin >> 6;
    const int i0 = (lin & 63) * 32;

    const int wv = tid >> 6;
    const int h  = hp * 2 + (wv >> 1);               // this wave's head
    const int isub = wv & 1;                         // i-subtile (16 rows)
    const int ln = tid & 63, l15 = ln & 15, l4 = ln >> 4;

    const int irow = i0 + isub * 16 + l15;           // lane's A-row (m = l15)
    const float ss = ssrc[(size_t)h * BN + (size_t)b * Nn + irow];
    const float* adjr = adj  + ((size_t)b * Nn + irow) * Nn + l4 * 8;
    const float* sdr  = sdst + (size_t)h * BN + (size_t)b * Nn + l4 * 8;
    // hbf is [b][jb(64)][dglob(256)][j(32)]; B-frag (t,kh): row h*64+t*16+l15,
    // elems j = l4*8..+8 of jb = 2*st+kh.
    const unsigned short* hb0 = hbf +
        ((size_t)b * 64 * 256 + (size_t)(h * HDd + l15)) * 32 + l4 * 8;

    const v8s ones = {0x3F80, 0x3F80, 0x3F80, 0x3F80, 0x3F80, 0x3F80, 0x3F80, 0x3F80};

    v4f acc[4], zac;
#pragma unroll
    for (int t = 0; t < 4; ++t) acc[t] = (v4f){0.f, 0.f, 0.f, 0.f};
    zac = (v4f){0.f, 0.f, 0.f, 0.f};

    v8s bA[8], bB[8];
    float4 ajA[4], sdA[4], ajB[4], sdB[4];

    // 16 vector loads per step, all issued one step ahead of use.
#define LOADS(stn, bb, aj_, sd_) do {                                         \
        const int js_ = (stn) & 31;                                           \
        const float* ap_ = adjr + js_ * 64;                                   \
        aj_[0] = *(const float4*)(ap_ + 0);                                   \
        aj_[1] = *(const float4*)(ap_ + 4);                                   \
        aj_[2] = *(const float4*)(ap_ + 32);                                  \
        aj_[3] = *(const float4*)(ap_ + 36);                                  \
        const float* sp_ = sdr + js_ * 64;                                    \
        sd_[0] = *(const float4*)(sp_ + 0);                                   \
        sd_[1] = *(const float4*)(sp_ + 4);                                   \
        sd_[2] = *(const float4*)(sp_ + 32);                                  \
        sd_[3] = *(const float4*)(sp_ + 36);                                  \
        const unsigned short* hq_ = hb0 + (size_t)js_ * 16384;                \
        bb[0] = *(const v8s*)(hq_ + 0);                                       \
        bb[1] = *(const v8s*)(hq_ + 8192);                                    \
        bb[2] = *(const v8s*)(hq_ + 512);                                     \
        bb[3] = *(const v8s*)(hq_ + 8192 + 512);                              \
        bb[4] = *(const v8s*)(hq_ + 1024);                                    \
        bb[5] = *(const v8s*)(hq_ + 8192 + 1024);                             \
        bb[6] = *(const v8s*)(hq_ + 1536);                                    \
        bb[7] = *(const v8s*)(hq_ + 8192 + 1536);                             \
    } while (0)

    // gen chain identical to v1: e=ss+sd; e=fmax(e,0.2e); w=adj*__expf(e); rne.
#define GENW(ssv, sdv, ajv) ({                                                \
        float e_ = (ssv) + (sdv);                                             \
        e_ = fmaxf(e_, 0.2f * e_);                                            \
        (ajv) * __expf(e_);                                                   \
    })

#define GENFRAG(dst, ajx, ajy, sdx, sdy) do {                                 \
        float w0_ = GENW(ss, sdx.x, ajx.x);                                   \
        float w1_ = GENW(ss, sdx.y, ajx.y);                                   \
        float w2_ = GENW(ss, sdx.z, ajx.z);                                   \
        float w3_ = GENW(ss, sdx.w, ajx.w);                                   \
        float w4_ = GENW(ss, sdy.x, ajy.x);                                   \
        float w5_ = GENW(ss, sdy.y, ajy.y);                                   \
        float w6_ = GENW(ss, sdy.z, ajy.z);                                   \
        float w7_ = GENW(ss, sdy.w, ajy.w);                                   \
        union { v8s v; unsigned u[4]; } P_;                                   \
        P_.u[0] = rne_bf16(w0_) | (rne_bf16(w1_) << 16);                      \
        P_.u[1] = rne_bf16(w2_) | (rne_bf16(w3_) << 16);                      \
        P_.u[2] = rne_bf16(w4_) | (rne_bf16(w5_) << 16);                      \
        P_.u[3] = rne_bf16(w6_) | (rne_bf16(w7_) << 16);                      \
        dst = P_.v;                                                           \
    } while (0)

#define STEP(bb, aj_, sd_) do {                                               \
        v8s afr0, afr1;                                                       \
        GENFRAG(afr0, aj_[0], aj_[1], sd_[0], sd_[1]);                        \
        GENFRAG(afr1, aj_[2], aj_[3], sd_[2], sd_[3]);                        \
        acc[0] = __builtin_amdgcn_mfma_f32_16x16x32_bf16(afr0, bb[0], acc[0], 0, 0, 0); \
        acc[1] = __builtin_amdgcn_mfma_f32_16x16x32_bf16(afr0, bb[2], acc[1], 0, 0, 0); \
        acc[2] = __builtin_amdgcn_mfma_f32_16x16x32_bf16(afr0, bb[4], acc[2], 0, 0, 0); \
        acc[3] = __builtin_amdgcn_mfma_f32_16x16x32_bf16(afr0, bb[6], acc[3], 0, 0, 0); \
        zac    = __builtin_amdgcn_mfma_f32_16x16x32_bf16(afr0, ones,  zac,    0, 0, 0); \
        acc[0] = __builtin_amdgcn_mfma_f32_16x16x32_bf16(afr1, bb[1], acc[0], 0, 0, 0); \
        acc[1] = __builtin_amdgcn_mfma_f32_16x16x32_bf16(afr1, bb[3], acc[1], 0, 0, 0); \
        acc[2] = __builtin_amdgcn_mfma_f32_16x16x32_bf16(afr1, bb[5], acc[2], 0, 0, 0); \
        acc[3] = __builtin_amdgcn_mfma_f32_16x16x32_bf16(afr1, bb[7], acc[3], 0, 0, 0); \
        zac    = __builtin_amdgcn_mfma_f32_16x16x32_bf16(afr1, ones,  zac,    0, 0, 0); \
    } while (0)

    LOADS(0, bA, ajA, sdA);
    for (int st = 0; st < 32; st += 2) {
        LOADS(st + 1, bB, ajB, sdB);   // in flight during STEP(A)
        STEP(bA, ajA, sdA);
        LOADS(st + 2, bA, ajA, sdA);   // wraps harmlessly to 0 at st=30
        STEP(bB, ajB, sdB);
    }

#undef LOADS
#undef GENW
#undef GENFRAG
#undef STEP

    // ---- epilogue: register-local normalize + exclusive store ----
    float zi[4];
#pragma unroll
    for (int r = 0; r < 4; ++r) zi[r] = 1.f / zac[r];
    float* op = out + ((size_t)b * Nn + i0 + isub * 16 + l4 * 4) * Dd + h * HDd + l15;
#pragma unroll
    for (int r = 0; r < 4; ++r)
#pragma unroll
        for (int t = 0; t < 4; ++t)
            op[(size_t)r * Dd + t * 16] = acc[t][r] * zi[r];
}

extern "C" void kernel_launch(void* const* d_in, const int* in_sizes, int n_in,
                              void* d_out, int out_size, void* d_ws, size_t ws_size,
                              hipStream_t stream) {
    const float* x     = (const float*)d_in[0];
    const float* adj   = (const float*)d_in[1];
    const float* W     = (const float*)d_in[2];
    const float* a_src = (const float*)d_in[3];
    const float* a_dst = (const float*)d_in[4];
    float* out = (float*)d_out;

    // ws: hbf 4MB | ssrc [h][bn] 128KB | sdst [h][bn] 128KB
    unsigned short* hbf = (unsigned short*)d_ws;
    float* ssrc = (float*)(hbf + (size_t)Bb * Nn * Dd);
    float* sdst = ssrc + (size_t)Hh * BN;

    k_gemm<<<dim3(512), dim3(256), 0, stream>>>(x, W, a_src, a_dst, hbf, ssrc, sdst);
    k_aggr<<<dim3(512), dim3(256), 0, stream>>>(hbf, adj, ssrc, sdst, out);
}

// Round 2
// 168.105 us; speedup vs baseline: 1.2364x; 1.2364x over previous
//
#include <hip/hip_runtime.h>
#include <math.h>

#define Bb   4
#define Nn   2048
#define Dd   256
#define Hh   4
#define HDd  64
#define BN   (Bb * Nn)

typedef float v4f __attribute__((ext_vector_type(4)));
typedef short v8s __attribute__((ext_vector_type(8)));

__device__ __forceinline__ unsigned rne_bf16(float f) {
    unsigned u = __float_as_uint(f);
    u += 0x7fffu + ((u >> 16) & 1u);
    return u >> 16;
}

// ---------------------------------------------------------------------------
// Kernel 1: h = x @ W.T via MFMA, hi/lo bf16 split (err ~2^-17).  UNCHANGED.
// ---------------------------------------------------------------------------
__global__ __launch_bounds__(256, 2) void k_gemm(const float* __restrict__ x,
                                                 const float* __restrict__ W,
                                                 const float* __restrict__ a_src,
                                                 const float* __restrict__ a_dst,
                                                 unsigned short* __restrict__ hbf,
                                                 float* __restrict__ ssrc,
                                                 float* __restrict__ sdst) {
    __shared__ __align__(16) unsigned short xs[2][64 * 72];  // hi, lo  (T reuses xs)
    __shared__ __align__(16) unsigned short wsm[2][64 * 72];
    __shared__ float asd[128];

    const int tid = threadIdx.x;
    const int m0 = (int)(blockIdx.x >> 2) * 64;
    const int head = (int)blockIdx.x & 3;
    const int n0 = head * 64;
    const int b = m0 >> 11;
    const int i0loc = m0 & 2047;

    if (tid < 128) {
        int sel = tid >> 6, d = tid & 63;
        asd[tid] = sel ? a_dst[n0 + d] : a_src[n0 + d];
    }

    const int wv = tid >> 6, ln = tid & 63, l15 = ln & 15, l4 = ln >> 4;
    const int mh = wv >> 1, nh = wv & 1;
    const int srow = tid >> 2, kq = (tid & 3) * 16;

    v4f acc[2][2];
#pragma unroll
    for (int g = 0; g < 2; ++g)
#pragma unroll
        for (int t = 0; t < 2; ++t) acc[g][t] = (v4f){0.f, 0.f, 0.f, 0.f};

    for (int st = 0; st < 4; ++st) {
        const int k0 = st * 64;
        __syncthreads();
        // ---- stage x and W tiles as bf16 hi/lo ----
        {
            float xf[16], wf[16];
            const float* xp = x + (size_t)(m0 + srow) * Dd + k0 + kq;
            const float* wp = W + (size_t)(n0 + srow) * Dd + k0 + kq;
#pragma unroll
            for (int q = 0; q < 4; ++q) {
                *(float4*)&xf[q * 4] = *(const float4*)(xp + q * 4);
                *(float4*)&wf[q * 4] = *(const float4*)(wp + q * 4);
            }
            unsigned xh[8], xl[8], wh[8], wl[8];
#pragma unroll
            for (int j = 0; j < 8; ++j) {
                unsigned h0 = rne_bf16(xf[2 * j]), h1 = rne_bf16(xf[2 * j + 1]);
                float l0 = xf[2 * j] - __uint_as_float(h0 << 16);
                float l1 = xf[2 * j + 1] - __uint_as_float(h1 << 16);
                xh[j] = h0 | (h1 << 16);
                xl[j] = rne_bf16(l0) | (rne_bf16(l1) << 16);
                unsigned g0 = rne_bf16(wf[2 * j]), g1 = rne_bf16(wf[2 * j + 1]);
                float m0f = wf[2 * j] - __uint_as_float(g0 << 16);
                float m1f = wf[2 * j + 1] - __uint_as_float(g1 << 16);
                wh[j] = g0 | (g1 << 16);
                wl[j] = rne_bf16(m0f) | (rne_bf16(m1f) << 16);
            }
            *(uint4*)(xs[0] + srow * 72 + kq)     = make_uint4(xh[0], xh[1], xh[2], xh[3]);
            *(uint4*)(xs[0] + srow * 72 + kq + 8) = make_uint4(xh[4], xh[5], xh[6], xh[7]);
            *(uint4*)(xs[1] + srow * 72 + kq)     = make_uint4(xl[0], xl[1], xl[2], xl[3]);
            *(uint4*)(xs[1] + srow * 72 + kq + 8) = make_uint4(xl[4], xl[5], xl[6], xl[7]);
            *(uint4*)(wsm[0] + srow * 72 + kq)     = make_uint4(wh[0], wh[1], wh[2], wh[3]);
            *(uint4*)(wsm[0] + srow * 72 + kq + 8) = make_uint4(wh[4], wh[5], wh[6], wh[7]);
            *(uint4*)(wsm[1] + srow * 72 + kq)     = make_uint4(wl[0], wl[1], wl[2], wl[3]);
            *(uint4*)(wsm[1] + srow * 72 + kq + 8) = make_uint4(wl[4], wl[5], wl[6], wl[7]);
        }
        __syncthreads();
        // ---- MFMA: wave (mh, nh) owns 2x2 16-tiles ----
        {
            v8s ah[2][2], al[2][2], bh_[2][2], bl_[2][2];
#pragma unroll
            for (int g = 0; g < 2; ++g)
#pragma unroll
                for (int kh = 0; kh < 2; ++kh) {
                    int ro = (mh * 32 + g * 16 + l15) * 72 + kh * 32 + l4 * 8;
                    ah[g][kh] = *(const v8s*)(xs[0] + ro);
                    al[g][kh] = *(const v8s*)(xs[1] + ro);
                }
#pragma unroll
            for (int t = 0; t < 2; ++t)
#pragma unroll
                for (int kh = 0; kh < 2; ++kh) {
                    int ro = (nh * 32 + t * 16 + l15) * 72 + kh * 32 + l4 * 8;
                    bh_[t][kh] = *(const v8s*)(wsm[0] + ro);
                    bl_[t][kh] = *(const v8s*)(wsm[1] + ro);
                }
#pragma unroll
            for (int g = 0; g < 2; ++g)
#pragma unroll
                for (int t = 0; t < 2; ++t)
#pragma unroll
                    for (int kh = 0; kh < 2; ++kh) {
                        acc[g][t] = __builtin_amdgcn_mfma_f32_16x16x32_bf16(ah[g][kh], bh_[t][kh], acc[g][t], 0, 0, 0);
                        acc[g][t] = __builtin_amdgcn_mfma_f32_16x16x32_bf16(al[g][kh], bh_[t][kh], acc[g][t], 0, 0, 0);
                        acc[g][t] = __builtin_amdgcn_mfma_f32_16x16x32_bf16(ah[g][kh], bl_[t][kh], acc[g][t], 0, 0, 0);
                    }
        }
    }

    // ---- epilogue: C -> T[d][m] (stride 67) ----
    __syncthreads();
    float* T = (float*)&xs[0][0];   // 64*67*4 = 17168 B
#pragma unroll
    for (int g = 0; g < 2; ++g)
#pragma unroll
        for (int t = 0; t < 2; ++t)
#pragma unroll
            for (int r = 0; r < 4; ++r) {
                int d = nh * 32 + t * 16 + l15;
                int m = mh * 32 + g * 16 + l4 * 4 + r;
                T[d * 67 + m] = acc[g][t][r];
            }
    __syncthreads();
    if (tid < 128) {
        // scores -> TRANSPOSED [h][bn]
        int m = tid & 63, sel = tid >> 6;
        float s = 0.f;
#pragma unroll
        for (int d = 0; d < 64; ++d) s += T[d * 67 + m] * asd[sel * 64 + d];
        (sel ? sdst : ssrc)[(size_t)head * BN + (size_t)b * Nn + i0loc + m] = s;
        // hbf pack
        int dloc = tid >> 1, jh = tid & 1;
        const float* row = T + dloc * 67 + jh * 32;
        unsigned pk[16];
#pragma unroll
        for (int jj = 0; jj < 16; ++jj)
            pk[jj] = rne_bf16(row[jj * 2]) | (rne_bf16(row[jj * 2 + 1]) << 16);
        unsigned short* dst = hbf +
            ((size_t)((b * 64 + (i0loc >> 5) + jh) * 256 + head * HDd + dloc)) * 32;
        uint4* d4 = (uint4*)dst;
        d4[0] = make_uint4(pk[0], pk[1], pk[2], pk[3]);
        d4[1] = make_uint4(pk[4], pk[5], pk[6], pk[7]);
        d4[2] = make_uint4(pk[8], pk[9], pk[10], pk[11]);
        d4[3] = make_uint4(pk[12], pk[13], pk[14], pk[15]);
    }
}

// ---------------------------------------------------------------------------
// Kernel 2 (v3): barrier-free register-direct gen (v2 idea) + restored TLP.
// Block = 512 thr = 8 waves = (4 heads) x (2 j-halves); i-tile 16; grid 512
// -> 4096 waves = 4 waves/SIMD (v1 occupancy, v2 structure).
// Register diet so the pipeline survives regalloc (v2's VGPR=52 sink bug):
//   - B-frags single-buffered (32 v), issued at step TOP; the ~350cy gen
//     VALU phase covers their L2 latency.
//   - adj (the HBM stream feeding gen) ping-pong prefetched (32 v).
//   - sdst staged once into LDS (32 KB) -> sd reads ride lgkmcnt, off the
//     vmcnt pipeline.  sched_barrier(0) pins loads above gen.
// z via ones-MFMA (no redundancy: each (h,jh) wave does its half once);
// j-half partials (acc+zac) combined via 20 KB LDS + one barrier.
// Numerics: gen chain bit-identical to v1/v2; only j-sum association
// changes ((jh0)+(jh1) vs sequential) -- f32 noise, well under tolerance.
// ---------------------------------------------------------------------------
__global__ __launch_bounds__(512, 4) void k_aggr(const unsigned short* __restrict__ hbf,
                                                 const float* __restrict__ adj,
                                                 const float* __restrict__ ssrc,
                                                 const float* __restrict__ sdst,
                                                 float* __restrict__ out) {
    __shared__ __align__(16) float sdl[4 * 2048];      // 32 KB sdst planes (this b)
    __shared__ __align__(16) float red[4 * 64 * 20];   // 20 KB jh-combine

    const int tid = threadIdx.x;
    const int bid = (int)blockIdx.x;
    const int b  = bid >> 7;
    const int i0 = (bid & 127) * 16;

    const int wv = tid >> 6;
    const int h  = wv & 3;                 // wave's head
    const int jh = wv >> 2;                // wave's j-half (16 steps of 64 j)
    const int ln = tid & 63, l15 = ln & 15, l4 = ln >> 4;

    // ---- stage sdst planes for this b into LDS (once) ----
    for (int q = tid; q < 2048; q += 512) {
        int hh = q >> 9, j = (q & 511) * 4;
        *(float4*)&sdl[hh * 2048 + j] =
            *(const float4*)(sdst + (size_t)hh * BN + (size_t)b * Nn + j);
    }

    const int irow = i0 + l15;             // lane's A-row (m = l15)
    const float ss = ssrc[(size_t)h * BN + (size_t)b * Nn + irow];
    const float* adjr = adj + ((size_t)b * Nn + irow) * Nn + jh * 1024 + l4 * 8;
    const unsigned short* hb0 = hbf +
        ((size_t)b * 64 * 256 + (size_t)(h * HDd + l15)) * 32 + l4 * 8;
    const float* sdb = sdl + h * 2048 + jh * 1024 + l4 * 8;

    const v8s ones = {0x3F80, 0x3F80, 0x3F80, 0x3F80, 0x3F80, 0x3F80, 0x3F80, 0x3F80};

    v4f acc0 = (v4f){0.f, 0.f, 0.f, 0.f}, acc1 = acc0, acc2 = acc0, acc3 = acc0, zac = acc0;
    v8s bb0, bb1, bb2, bb3, bb4, bb5, bb6, bb7;
    float4 ajA0, ajA1, ajA2, ajA3, ajB0, ajB1, ajB2, ajB3;

    __syncthreads();   // sdl ready

#define LOADB(S_) do {                                                        \
        const unsigned short* hq_ = hb0 + (size_t)(jh * 16 + (S_)) * 16384;   \
        bb0 = *(const v8s*)(hq_ + 0);                                         \
        bb1 = *(const v8s*)(hq_ + 8192);                                      \
        bb2 = *(const v8s*)(hq_ + 512);                                       \
        bb3 = *(const v8s*)(hq_ + 8192 + 512);                                \
        bb4 = *(const v8s*)(hq_ + 1024);                                      \
        bb5 = *(const v8s*)(hq_ + 8192 + 1024);                               \
        bb6 = *(const v8s*)(hq_ + 1536);                                      \
        bb7 = *(const v8s*)(hq_ + 8192 + 1536);                               \
    } while (0)

#define LOADADJ(S_, A0_, A1_, A2_, A3_) do {                                  \
        const float* ap_ = adjr + ((S_) & 15) * 64;                           \
        A0_ = *(const float4*)(ap_);                                          \
        A1_ = *(const float4*)(ap_ + 4);                                      \
        A2_ = *(const float4*)(ap_ + 32);                                     \
        A3_ = *(const float4*)(ap_ + 36);                                     \
    } while (0)

    // gen chain identical to v1/v2: e=ss+sd; e=fmax(e,0.2e); w=adj*__expf(e); rne.
#define GENW(ssv, sdv, ajv) ({                                                \
        float e_ = (ssv) + (sdv);                                             \
        e_ = fmaxf(e_, 0.2f * e_);                                            \
        (ajv) * __expf(e_);                                                   \
    })

#define GENFRAG(dst, ajx, ajy, sdx, sdy) do {                                 \
        float w0_ = GENW(ss, sdx.x, ajx.x);                                   \
        float w1_ = GENW(ss, sdx.y, ajx.y);                                   \
        float w2_ = GENW(ss, sdx.z, ajx.z);                                   \
        float w3_ = GENW(ss, sdx.w, ajx.w);                                   \
        float w4_ = GENW(ss, sdy.x, ajy.x);                                   \
        float w5_ = GENW(ss, sdy.y, ajy.y);                                   \
        float w6_ = GENW(ss, sdy.z, ajy.z);                                   \
        float w7_ = GENW(ss, sdy.w, ajy.w);                                   \
        union { v8s v; unsigned u[4]; } P_;                                   \
        P_.u[0] = rne_bf16(w0_) | (rne_bf16(w1_) << 16);                      \
        P_.u[1] = rne_bf16(w2_) | (rne_bf16(w3_) << 16);                      \
        P_.u[2] = rne_bf16(w4_) | (rne_bf16(w5_) << 16);                      \
        P_.u[3] = rne_bf16(w6_) | (rne_bf16(w7_) << 16);                      \
        dst = P_.v;                                                           \
    } while (0)

#define STEPX(S_, A0_, A1_, A2_, A3_) do {                                    \
        const float* sdp_ = sdb + (S_) * 64;                                  \
        const float4 sd0_ = *(const float4*)(sdp_);                           \
        const float4 sd1_ = *(const float4*)(sdp_ + 4);                       \
        const float4 sd2_ = *(const float4*)(sdp_ + 32);                      \
        const float4 sd3_ = *(const float4*)(sdp_ + 36);                      \
        v8s afr0_, afr1_;                                                     \
        GENFRAG(afr0_, A0_, A1_, sd0_, sd1_);                                 \
        GENFRAG(afr1_, A2_, A3_, sd2_, sd3_);                                 \
        acc0 = __builtin_amdgcn_mfma_f32_16x16x32_bf16(afr0_, bb0, acc0, 0, 0, 0); \
        acc1 = __builtin_amdgcn_mfma_f32_16x16x32_bf16(afr0_, bb2, acc1, 0, 0, 0); \
        acc2 = __builtin_amdgcn_mfma_f32_16x16x32_bf16(afr0_, bb4, acc2, 0, 0, 0); \
        acc3 = __builtin_amdgcn_mfma_f32_16x16x32_bf16(afr0_, bb6, acc3, 0, 0, 0); \
        zac  = __builtin_amdgcn_mfma_f32_16x16x32_bf16(afr0_, ones, zac, 0, 0, 0); \
        acc0 = __builtin_amdgcn_mfma_f32_16x16x32_bf16(afr1_, bb1, acc0, 0, 0, 0); \
        acc1 = __builtin_amdgcn_mfma_f32_16x16x32_bf16(afr1_, bb3, acc1, 0, 0, 0); \
        acc2 = __builtin_amdgcn_mfma_f32_16x16x32_bf16(afr1_, bb5, acc2, 0, 0, 0); \
        acc3 = __builtin_amdgcn_mfma_f32_16x16x32_bf16(afr1_, bb7, acc3, 0, 0, 0); \
        zac  = __builtin_amdgcn_mfma_f32_16x16x32_bf16(afr1_, ones, zac, 0, 0, 0); \
    } while (0)

    LOADADJ(0, ajA0, ajA1, ajA2, ajA3);
#pragma unroll 1
    for (int s = 0; s < 16; s += 2) {
        LOADB(s);                                     // covered by gen below
        LOADADJ(s + 1, ajB0, ajB1, ajB2, ajB3);       // next-step adj in flight
        __builtin_amdgcn_sched_barrier(0);            // pin loads above gen
        STEPX(s, ajA0, ajA1, ajA2, ajA3);
        LOADB(s + 1);
        LOADADJ(s + 2, ajA0, ajA1, ajA2, ajA3);       // s=14 -> wraps to 0, harmless
        __builtin_amdgcn_sched_barrier(0);
        STEPX(s + 1, ajB0, ajB1, ajB2, ajB3);
    }

#undef LOADB
#undef LOADADJ
#undef GENW
#undef GENFRAG
#undef STEPX

    // ---- combine j-halves via LDS, then normalize + exclusive store ----
    float* rp = red + (h * 64 + ln) * 20;
    if (jh) {
        *(v4f*)(rp + 0)  = acc0;
        *(v4f*)(rp + 4)  = acc1;
        *(v4f*)(rp + 8)  = acc2;
        *(v4f*)(rp + 12) = acc3;
        *(v4f*)(rp + 16) = zac;
    }
    __syncthreads();
    if (!jh) {
        acc0 += *(const v4f*)(rp + 0);
        acc1 += *(const v4f*)(rp + 4);
        acc2 += *(const v4f*)(rp + 8);
        acc3 += *(const v4f*)(rp + 12);
        zac  += *(const v4f*)(rp + 16);
        float zi[4];
#pragma unroll
        for (int r = 0; r < 4; ++r) zi[r] = 1.f / zac[r];
        float* op = out + ((size_t)b * Nn + i0 + l4 * 4) * Dd + h * HDd + l15;
#pragma unroll
        for (int r = 0; r < 4; ++r) {
            op[(size_t)r * Dd + 0]  = acc0[r] * zi[r];
            op[(size_t)r * Dd + 16] = acc1[r] * zi[r];
            op[(size_t)r * Dd + 32] = acc2[r] * zi[r];
            op[(size_t)r * Dd + 48] = acc3[r] * zi[r];
        }
    }
}

extern "C" void kernel_launch(void* const* d_in, const int* in_sizes, int n_in,
                              void* d_out, int out_size, void* d_ws, size_t ws_size,
                              hipStream_t stream) {
    const float* x     = (const float*)d_in[0];
    const float* adj   = (const float*)d_in[1];
    const float* W     = (const float*)d_in[2];
    const float* a_src = (const float*)d_in[3];
    const float* a_dst = (const float*)d_in[4];
    float* out = (float*)d_out;

    // ws: hbf 4MB | ssrc [h][bn] 128KB | sdst [h][bn] 128KB
    unsigned short* hbf = (unsigned short*)d_ws;
    float* ssrc = (float*)(hbf + (size_t)Bb * Nn * Dd);
    float* sdst = ssrc + (size_t)Hh * BN;

    k_gemm<<<dim3(512), dim3(256), 0, stream>>>(x, W, a_src, a_dst, hbf, ssrc, sdst);
    k_aggr<<<dim3(512), dim3(512), 0, stream>>>(hbf, adj, ssrc, sdst, out);
}

// Round 3
// 154.625 us; speedup vs baseline: 1.3442x; 1.0872x over previous
//
#include <hip/hip_runtime.h>
#include <math.h>

#define Bb   4
#define Nn   2048
#define Dd   256
#define Hh   4
#define HDd  64
#define BN   (Bb * Nn)

typedef float v4f __attribute__((ext_vector_type(4)));
typedef short v8s __attribute__((ext_vector_type(8)));

__device__ __forceinline__ unsigned rne_bf16(float f) {
    unsigned u = __float_as_uint(f);
    u += 0x7fffu + ((u >> 16) & 1u);
    return u >> 16;
}

// ---------------------------------------------------------------------------
// Kernel 1: h = x @ W.T via MFMA (blocks 0..511, UNCHANGED logic)
//           + fused adj->bitmask compress stream (blocks 512..2559).
// The compress blocks use the idle HBM bandwidth while gemm blocks compute:
// adj is {0,1} f32 (67 MB) -> 1 bit/entry (2.1 MB) via __ballot, so k_aggr
// never has to stream adj from HBM again.
// ---------------------------------------------------------------------------
__global__ __launch_bounds__(256, 2) void k_gemm(const float* __restrict__ x,
                                                 const float* __restrict__ W,
                                                 const float* __restrict__ a_src,
                                                 const float* __restrict__ a_dst,
                                                 const float* __restrict__ adj,
                                                 unsigned short* __restrict__ hbf,
                                                 float* __restrict__ ssrc,
                                                 float* __restrict__ sdst,
                                                 unsigned long long* __restrict__ bitadj) {
    __shared__ __align__(16) unsigned short xs[2][64 * 72];  // hi, lo  (T reuses xs)
    __shared__ __align__(16) unsigned short wsm[2][64 * 72];
    __shared__ float asd[128];

    if (blockIdx.x >= 512) {
        // ---- adj f32 -> bitmask. word w covers row (w>>5), j in [(w&31)*64, +64).
        // 262144 words total; 8192 compress waves x 8 iters x 4 words.
        const int gw = ((int)blockIdx.x - 512) * 4 + ((int)threadIdx.x >> 6);
        const int lane = (int)threadIdx.x & 63;
#pragma unroll 1
        for (int w = gw * 4; w < 262144; w += 8192 * 4) {
            float v0 = adj[(size_t)((w + 0) >> 5) * 2048 + ((w + 0) & 31) * 64 + lane];
            float v1 = adj[(size_t)((w + 1) >> 5) * 2048 + ((w + 1) & 31) * 64 + lane];
            float v2 = adj[(size_t)((w + 2) >> 5) * 2048 + ((w + 2) & 31) * 64 + lane];
            float v3 = adj[(size_t)((w + 3) >> 5) * 2048 + ((w + 3) & 31) * 64 + lane];
            unsigned long long m0 = __ballot(v0 != 0.0f);
            unsigned long long m1 = __ballot(v1 != 0.0f);
            unsigned long long m2 = __ballot(v2 != 0.0f);
            unsigned long long m3 = __ballot(v3 != 0.0f);
            if (lane == 0) {
                bitadj[w + 0] = m0;
                bitadj[w + 1] = m1;
                bitadj[w + 2] = m2;
                bitadj[w + 3] = m3;
            }
        }
        return;
    }

    const int tid = threadIdx.x;
    const int m0 = (int)(blockIdx.x >> 2) * 64;
    const int head = (int)blockIdx.x & 3;
    const int n0 = head * 64;
    const int b = m0 >> 11;
    const int i0loc = m0 & 2047;

    if (tid < 128) {
        int sel = tid >> 6, d = tid & 63;
        asd[tid] = sel ? a_dst[n0 + d] : a_src[n0 + d];
    }

    const int wv = tid >> 6, ln = tid & 63, l15 = ln & 15, l4 = ln >> 4;
    const int mh = wv >> 1, nh = wv & 1;
    const int srow = tid >> 2, kq = (tid & 3) * 16;

    v4f acc[2][2];
#pragma unroll
    for (int g = 0; g < 2; ++g)
#pragma unroll
        for (int t = 0; t < 2; ++t) acc[g][t] = (v4f){0.f, 0.f, 0.f, 0.f};

    for (int st = 0; st < 4; ++st) {
        const int k0 = st * 64;
        __syncthreads();
        // ---- stage x and W tiles as bf16 hi/lo ----
        {
            float xf[16], wf[16];
            const float* xp = x + (size_t)(m0 + srow) * Dd + k0 + kq;
            const float* wp = W + (size_t)(n0 + srow) * Dd + k0 + kq;
#pragma unroll
            for (int q = 0; q < 4; ++q) {
                *(float4*)&xf[q * 4] = *(const float4*)(xp + q * 4);
                *(float4*)&wf[q * 4] = *(const float4*)(wp + q * 4);
            }
            unsigned xh[8], xl[8], wh[8], wl[8];
#pragma unroll
            for (int j = 0; j < 8; ++j) {
                unsigned h0 = rne_bf16(xf[2 * j]), h1 = rne_bf16(xf[2 * j + 1]);
                float l0 = xf[2 * j] - __uint_as_float(h0 << 16);
                float l1 = xf[2 * j + 1] - __uint_as_float(h1 << 16);
                xh[j] = h0 | (h1 << 16);
                xl[j] = rne_bf16(l0) | (rne_bf16(l1) << 16);
                unsigned g0 = rne_bf16(wf[2 * j]), g1 = rne_bf16(wf[2 * j + 1]);
                float m0f = wf[2 * j] - __uint_as_float(g0 << 16);
                float m1f = wf[2 * j + 1] - __uint_as_float(g1 << 16);
                wh[j] = g0 | (g1 << 16);
                wl[j] = rne_bf16(m0f) | (rne_bf16(m1f) << 16);
            }
            *(uint4*)(xs[0] + srow * 72 + kq)     = make_uint4(xh[0], xh[1], xh[2], xh[3]);
            *(uint4*)(xs[0] + srow * 72 + kq + 8) = make_uint4(xh[4], xh[5], xh[6], xh[7]);
            *(uint4*)(xs[1] + srow * 72 + kq)     = make_uint4(xl[0], xl[1], xl[2], xl[3]);
            *(uint4*)(xs[1] + srow * 72 + kq + 8) = make_uint4(xl[4], xl[5], xl[6], xl[7]);
            *(uint4*)(wsm[0] + srow * 72 + kq)     = make_uint4(wh[0], wh[1], wh[2], wh[3]);
            *(uint4*)(wsm[0] + srow * 72 + kq + 8) = make_uint4(wh[4], wh[5], wh[6], wh[7]);
            *(uint4*)(wsm[1] + srow * 72 + kq)     = make_uint4(wl[0], wl[1], wl[2], wl[3]);
            *(uint4*)(wsm[1] + srow * 72 + kq + 8) = make_uint4(wl[4], wl[5], wl[6], wl[7]);
        }
        __syncthreads();
        // ---- MFMA: wave (mh, nh) owns 2x2 16-tiles ----
        {
            v8s ah[2][2], al[2][2], bh_[2][2], bl_[2][2];
#pragma unroll
            for (int g = 0; g < 2; ++g)
#pragma unroll
                for (int kh = 0; kh < 2; ++kh) {
                    int ro = (mh * 32 + g * 16 + l15) * 72 + kh * 32 + l4 * 8;
                    ah[g][kh] = *(const v8s*)(xs[0] + ro);
                    al[g][kh] = *(const v8s*)(xs[1] + ro);
                }
#pragma unroll
            for (int t = 0; t < 2; ++t)
#pragma unroll
                for (int kh = 0; kh < 2; ++kh) {
                    int ro = (nh * 32 + t * 16 + l15) * 72 + kh * 32 + l4 * 8;
                    bh_[t][kh] = *(const v8s*)(wsm[0] + ro);
                    bl_[t][kh] = *(const v8s*)(wsm[1] + ro);
                }
#pragma unroll
            for (int g = 0; g < 2; ++g)
#pragma unroll
                for (int t = 0; t < 2; ++t)
#pragma unroll
                    for (int kh = 0; kh < 2; ++kh) {
                        acc[g][t] = __builtin_amdgcn_mfma_f32_16x16x32_bf16(ah[g][kh], bh_[t][kh], acc[g][t], 0, 0, 0);
                        acc[g][t] = __builtin_amdgcn_mfma_f32_16x16x32_bf16(al[g][kh], bh_[t][kh], acc[g][t], 0, 0, 0);
                        acc[g][t] = __builtin_amdgcn_mfma_f32_16x16x32_bf16(ah[g][kh], bl_[t][kh], acc[g][t], 0, 0, 0);
                    }
        }
    }

    // ---- epilogue: C -> T[d][m] (stride 67) ----
    __syncthreads();
    float* T = (float*)&xs[0][0];   // 64*67*4 = 17168 B
#pragma unroll
    for (int g = 0; g < 2; ++g)
#pragma unroll
        for (int t = 0; t < 2; ++t)
#pragma unroll
            for (int r = 0; r < 4; ++r) {
                int d = nh * 32 + t * 16 + l15;
                int m = mh * 32 + g * 16 + l4 * 4 + r;
                T[d * 67 + m] = acc[g][t][r];
            }
    __syncthreads();
    if (tid < 128) {
        // scores -> TRANSPOSED [h][bn]
        int m = tid & 63, sel = tid >> 6;
        float s = 0.f;
#pragma unroll
        for (int d = 0; d < 64; ++d) s += T[d * 67 + m] * asd[sel * 64 + d];
        (sel ? sdst : ssrc)[(size_t)head * BN + (size_t)b * Nn + i0loc + m] = s;
        // hbf pack
        int dloc = tid >> 1, jh = tid & 1;
        const float* row = T + dloc * 67 + jh * 32;
        unsigned pk[16];
#pragma unroll
        for (int jj = 0; jj < 16; ++jj)
            pk[jj] = rne_bf16(row[jj * 2]) | (rne_bf16(row[jj * 2 + 1]) << 16);
        unsigned short* dst = hbf +
            ((size_t)((b * 64 + (i0loc >> 5) + jh) * 256 + head * HDd + dloc)) * 32;
        uint4* d4 = (uint4*)dst;
        d4[0] = make_uint4(pk[0], pk[1], pk[2], pk[3]);
        d4[1] = make_uint4(pk[4], pk[5], pk[6], pk[7]);
        d4[2] = make_uint4(pk[8], pk[9], pk[10], pk[11]);
        d4[3] = make_uint4(pk[12], pk[13], pk[14], pk[15]);
    }
}

// ---------------------------------------------------------------------------
// Kernel 2 (v4): v3 structure, but adj comes from the 2.1 MB bitmask
// (L2-resident) instead of the 67 MB f32 HBM stream that was the v3 wall.
// Per step per lane: ONE 8-byte broadcast load (all 4 l4-lanes share it).
// w = bit ? exp(e) : 0 is bit-identical to w = adj*exp(e) for adj in {0,1}.
// Register demand drops (aj ping-pong 16->4 VGPR + 8 hoisted masks), so the
// prefetch pipeline fits comfortably under the 128-VGPR launch-bounds cap.
// ---------------------------------------------------------------------------
__global__ __launch_bounds__(512, 4) void k_aggr(const unsigned short* __restrict__ hbf,
                                                 const unsigned long long* __restrict__ bitadj,
                                                 const float* __restrict__ ssrc,
                                                 const float* __restrict__ sdst,
                                                 float* __restrict__ out) {
    __shared__ __align__(16) float sdl[4 * 2048];      // 32 KB sdst planes (this b)
    __shared__ __align__(16) float red[4 * 64 * 20];   // 20 KB jh-combine

    const int tid = threadIdx.x;
    const int bid = (int)blockIdx.x;
    const int b  = bid >> 7;
    const int i0 = (bid & 127) * 16;

    const int wv = tid >> 6;
    const int h  = wv & 3;                 // wave's head
    const int jh = wv >> 2;                // wave's j-half (16 steps of 64 j)
    const int ln = tid & 63, l15 = ln & 15, l4 = ln >> 4;

    // ---- stage sdst planes for this b into LDS (once) ----
    for (int q = tid; q < 2048; q += 512) {
        int hh = q >> 9, j = (q & 511) * 4;
        *(float4*)&sdl[hh * 2048 + j] =
            *(const float4*)(sdst + (size_t)hh * BN + (size_t)b * Nn + j);
    }

    const int irow = i0 + l15;             // lane's A-row (m = l15)
    const float ss = ssrc[(size_t)h * BN + (size_t)b * Nn + irow];
    // bitmask row: 256 B/row; this wave's jh half starts at +jh*128.
    const unsigned char* ajr = (const unsigned char*)bitadj +
        ((size_t)b * Nn + irow) * 256 + jh * 128;
    const unsigned short* hb0 = hbf +
        ((size_t)b * 64 * 256 + (size_t)(h * HDd + l15)) * 32 + l4 * 8;
    const float* sdb = sdl + h * 2048 + jh * 1024 + l4 * 8;
    const unsigned mbase = 1u << (l4 * 8);   // lane's bit base within step word

    const v8s ones = {0x3F80, 0x3F80, 0x3F80, 0x3F80, 0x3F80, 0x3F80, 0x3F80, 0x3F80};

    v4f acc0 = (v4f){0.f, 0.f, 0.f, 0.f}, acc1 = acc0, acc2 = acc0, acc3 = acc0, zac = acc0;
    v8s bb0, bb1, bb2, bb3, bb4, bb5, bb6, bb7;
    uint2 ajA, ajB;

    __syncthreads();   // sdl ready

#define LOADB(S_) do {                                                        \
        const unsigned short* hq_ = hb0 + (size_t)(jh * 16 + (S_)) * 16384;   \
        bb0 = *(const v8s*)(hq_ + 0);                                         \
        bb1 = *(const v8s*)(hq_ + 8192);                                      \
        bb2 = *(const v8s*)(hq_ + 512);                                       \
        bb3 = *(const v8s*)(hq_ + 8192 + 512);                                \
        bb4 = *(const v8s*)(hq_ + 1024);                                      \
        bb5 = *(const v8s*)(hq_ + 8192 + 1024);                               \
        bb6 = *(const v8s*)(hq_ + 1536);                                      \
        bb7 = *(const v8s*)(hq_ + 8192 + 1536);                               \
    } while (0)

#define LOADADJ(S_, A_) do {                                                  \
        A_ = *(const uint2*)(ajr + ((S_) & 15) * 8);                          \
    } while (0)

    // gen chain identical to v1-v3: e=ss+sd; e=fmax(e,0.2e); p=__expf(e);
    // w = bit ? p : 0  ==  adj*p bitwise for adj in {0,1}.
#define GENP(sdv) ({                                                          \
        float e_ = ss + (sdv);                                                \
        e_ = fmaxf(e_, 0.2f * e_);                                            \
        __expf(e_);                                                           \
    })

#define SEL(W_, K_, P_) (((W_) & (mbase << (K_))) ? (P_) : 0.0f)

#define GENFRAG(dst, W_, sdx, sdy) do {                                       \
        float p0_ = GENP(sdx.x), p1_ = GENP(sdx.y);                           \
        float p2_ = GENP(sdx.z), p3_ = GENP(sdx.w);                           \
        float p4_ = GENP(sdy.x), p5_ = GENP(sdy.y);                           \
        float p6_ = GENP(sdy.z), p7_ = GENP(sdy.w);                           \
        float w0_ = SEL(W_, 0, p0_), w1_ = SEL(W_, 1, p1_);                   \
        float w2_ = SEL(W_, 2, p2_), w3_ = SEL(W_, 3, p3_);                   \
        float w4_ = SEL(W_, 4, p4_), w5_ = SEL(W_, 5, p5_);                   \
        float w6_ = SEL(W_, 6, p6_), w7_ = SEL(W_, 7, p7_);                   \
        union { v8s v; unsigned u[4]; } P_;                                   \
        P_.u[0] = rne_bf16(w0_) | (rne_bf16(w1_) << 16);                      \
        P_.u[1] = rne_bf16(w2_) | (rne_bf16(w3_) << 16);                      \
        P_.u[2] = rne_bf16(w4_) | (rne_bf16(w5_) << 16);                      \
        P_.u[3] = rne_bf16(w6_) | (rne_bf16(w7_) << 16);                      \
        dst = P_.v;                                                           \
    } while (0)

#define STEPX(S_, AJ_) do {                                                   \
        const float* sdp_ = sdb + (S_) * 64;                                  \
        const float4 sd0_ = *(const float4*)(sdp_);                           \
        const float4 sd1_ = *(const float4*)(sdp_ + 4);                       \
        const float4 sd2_ = *(const float4*)(sdp_ + 32);                      \
        const float4 sd3_ = *(const float4*)(sdp_ + 36);                      \
        v8s afr0_, afr1_;                                                     \
        GENFRAG(afr0_, AJ_.x, sd0_, sd1_);                                    \
        GENFRAG(afr1_, AJ_.y, sd2_, sd3_);                                    \
        acc0 = __builtin_amdgcn_mfma_f32_16x16x32_bf16(afr0_, bb0, acc0, 0, 0, 0); \
        acc1 = __builtin_amdgcn_mfma_f32_16x16x32_bf16(afr0_, bb2, acc1, 0, 0, 0); \
        acc2 = __builtin_amdgcn_mfma_f32_16x16x32_bf16(afr0_, bb4, acc2, 0, 0, 0); \
        acc3 = __builtin_amdgcn_mfma_f32_16x16x32_bf16(afr0_, bb6, acc3, 0, 0, 0); \
        zac  = __builtin_amdgcn_mfma_f32_16x16x32_bf16(afr0_, ones, zac, 0, 0, 0); \
        acc0 = __builtin_amdgcn_mfma_f32_16x16x32_bf16(afr1_, bb1, acc0, 0, 0, 0); \
        acc1 = __builtin_amdgcn_mfma_f32_16x16x32_bf16(afr1_, bb3, acc1, 0, 0, 0); \
        acc2 = __builtin_amdgcn_mfma_f32_16x16x32_bf16(afr1_, bb5, acc2, 0, 0, 0); \
        acc3 = __builtin_amdgcn_mfma_f32_16x16x32_bf16(afr1_, bb7, acc3, 0, 0, 0); \
        zac  = __builtin_amdgcn_mfma_f32_16x16x32_bf16(afr1_, ones, zac, 0, 0, 0); \
    } while (0)

    LOADADJ(0, ajA);
#pragma unroll 1
    for (int s = 0; s < 16; s += 2) {
        LOADB(s);                                     // covered by gen below
        LOADADJ(s + 1, ajB);                          // next-step mask in flight
        __builtin_amdgcn_sched_barrier(0);            // pin loads above gen
        STEPX(s, ajA);
        LOADB(s + 1);
        LOADADJ(s + 2, ajA);                          // s=14 -> wraps to 0, harmless
        __builtin_amdgcn_sched_barrier(0);
        STEPX(s + 1, ajB);
    }

#undef LOADB
#undef LOADADJ
#undef GENP
#undef SEL
#undef GENFRAG
#undef STEPX

    // ---- combine j-halves via LDS, then normalize + exclusive store ----
    float* rp = red + (h * 64 + ln) * 20;
    if (jh) {
        *(v4f*)(rp + 0)  = acc0;
        *(v4f*)(rp + 4)  = acc1;
        *(v4f*)(rp + 8)  = acc2;
        *(v4f*)(rp + 12) = acc3;
        *(v4f*)(rp + 16) = zac;
    }
    __syncthreads();
    if (!jh) {
        acc0 += *(const v4f*)(rp + 0);
        acc1 += *(const v4f*)(rp + 4);
        acc2 += *(const v4f*)(rp + 8);
        acc3 += *(const v4f*)(rp + 12);
        zac  += *(const v4f*)(rp + 16);
        float zi[4];
#pragma unroll
        for (int r = 0; r < 4; ++r) zi[r] = 1.f / zac[r];
        float* op = out + ((size_t)b * Nn + i0 + l4 * 4) * Dd + h * HDd + l15;
#pragma unroll
        for (int r = 0; r < 4; ++r) {
            op[(size_t)r * Dd + 0]  = acc0[r] * zi[r];
            op[(size_t)r * Dd + 16] = acc1[r] * zi[r];
            op[(size_t)r * Dd + 32] = acc2[r] * zi[r];
            op[(size_t)r * Dd + 48] = acc3[r] * zi[r];
        }
    }
}

extern "C" void kernel_launch(void* const* d_in, const int* in_sizes, int n_in,
                              void* d_out, int out_size, void* d_ws, size_t ws_size,
                              hipStream_t stream) {
    const float* x     = (const float*)d_in[0];
    const float* adj   = (const float*)d_in[1];
    const float* W     = (const float*)d_in[2];
    const float* a_src = (const float*)d_in[3];
    const float* a_dst = (const float*)d_in[4];
    float* out = (float*)d_out;

    // ws: hbf 4MB | ssrc [h][bn] 128KB | sdst [h][bn] 128KB | bitadj 2MB
    unsigned short* hbf = (unsigned short*)d_ws;
    float* ssrc = (float*)(hbf + (size_t)Bb * Nn * Dd);
    float* sdst = ssrc + (size_t)Hh * BN;
    unsigned long long* bitadj = (unsigned long long*)(sdst + (size_t)Hh * BN);

    k_gemm<<<dim3(2560), dim3(256), 0, stream>>>(x, W, a_src, a_dst, adj,
                                                 hbf, ssrc, sdst, bitadj);
    k_aggr<<<dim3(512), dim3(512), 0, stream>>>(hbf, bitadj, ssrc, sdst, out);
}